// Round 5
// baseline (189.003 us; speedup 1.0000x reference)
//
#include <hip/hip_runtime.h>

#define E_DIM 128
#define L_DIM 64
#define HDIM 64

__device__ __forceinline__ float waveSum(float v) {
#pragma unroll
  for (int o = 32; o > 0; o >>= 1) v += __shfl_xor(v, o);
  return v;
}
__device__ __forceinline__ float waveMax(float v) {
#pragma unroll
  for (int o = 32; o > 0; o >>= 1) v = fmaxf(v, __shfl_xor(v, o));
  return v;
}
__device__ __forceinline__ float halfSum(float v) {  // reduce within 32 lanes
#pragma unroll
  for (int o = 16; o > 0; o >>= 1) v += __shfl_xor(v, o);
  return v;
}
__device__ __forceinline__ float halfMax(float v) {  // max within 32 lanes
#pragma unroll
  for (int o = 16; o > 0; o >>= 1) v = fmaxf(v, __shfl_xor(v, o));
  return v;
}

// ---------------------------------------------------------------------------
// R18. Ledger: R14 contended global atomics = +23 µs. R16 coop grid.sync =
// 2x worse (spin-storm on one device-scope line across 8 XCDs). R17 int8
// rows (128 B = 1 line) = phase1 69.5->58 µs, FETCH 160->86 MB, absmax
// UNCHANGED 0.0078.
// R17 post-mortem: instruction count identical to bf16, bytes halved, time
// only -17%; delivered BW 2.8 TB/s < bf16's proven 4.8 -> NOT byte-bound;
// VALUBusy 31% -> LATENCY-bound on 16 dependent depth-1 gather windows.
// R18 change: gather = 8-lane/eighth-wave uint4 row loads (8 rows per wave
// instruction, 8 iterations) instead of 16-lane uint2 (4 rows, 16 iters).
// Same bytes, HALF the latency windows, 2x compute per window to hide
// latency under. (R13's "depth-2 neutral" was the byte-saturated bf16
// regime; doesn't bind here.)
// ---------------------------------------------------------------------------

// Convert pass: half-wave h handles global row 2*gw+h; user rows first,
// then item rows. Lane j covers dims 4j..4j+3. Row max via halfMax
// butterfly; int8 quantize + pack 4/lane; projections from fp32 values.
__global__ __launch_bounds__(256) void convert_i8(
    const float* __restrict__ user_src, const float* __restrict__ item_src,
    signed char* __restrict__ user_q, signed char* __restrict__ item_q,
    float* __restrict__ user_s, float* __restrict__ item_s,
    const float* __restrict__ w_uu, const float* __restrict__ w_uiu,
    const float* __restrict__ w_uui, float* __restrict__ pU0,
    float* __restrict__ pU1, float* __restrict__ pU2,
    float* __restrict__ pI1, float* __restrict__ pI2, int nUr, int nIr) {
  const int lane = threadIdx.x & 63;
  const int j = lane & 31;
  const int h = lane >> 5;
  const int gw = blockIdx.x * 4 + (threadIdx.x >> 6);
  const int r_all = gw * 2 + h;
  if (r_all >= nUr + nIr) return;

  const bool is_user = (r_all < nUr);
  const int r = is_user ? r_all : r_all - nUr;
  const float* src = is_user ? user_src : item_src;
  signed char* dst = is_user ? user_q : item_q;

  const float4 v = *(const float4*)(src + (long)r * E_DIM + j * 4);

  // ---- per-row absmax -> scale ----
  float am =
      fmaxf(fmaxf(fabsf(v.x), fabsf(v.y)), fmaxf(fabsf(v.z), fabsf(v.w)));
  am = halfMax(am);
  const float s = am * (1.0f / 127.0f);
  const float inv = (am > 0.f) ? 127.0f / am : 0.f;

  int q0 = __float2int_rn(v.x * inv);
  int q1 = __float2int_rn(v.y * inv);
  int q2 = __float2int_rn(v.z * inv);
  int q3 = __float2int_rn(v.w * inv);
  q0 = max(-127, min(127, q0));
  q1 = max(-127, min(127, q1));
  q2 = max(-127, min(127, q2));
  q3 = max(-127, min(127, q3));
  const unsigned int pk = (unsigned int)(q0 & 255) |
                          ((unsigned int)(q1 & 255) << 8) |
                          ((unsigned int)(q2 & 255) << 16) |
                          ((unsigned int)(q3 & 255) << 24);
  ((unsigned int*)dst)[(long)r * (E_DIM / 4) + j] = pk;

  // ---- projections from ORIGINAL fp32 values (reference-consistent) ----
  const float* wA = is_user ? w_uu : w_uiu;
  const float* wB = is_user ? w_uiu : w_uui;
  const float4 a4 = *(const float4*)(wA + E_DIM + j * 4);
  const float dA = halfSum(v.x * a4.x + v.y * a4.y + v.z * a4.z + v.w * a4.w);
  const float4 b4 = *(const float4*)(wB + E_DIM + j * 4);
  const float dB = halfSum(v.x * b4.x + v.y * b4.y + v.z * b4.z + v.w * b4.w);
  float dC = 0.f;
  if (is_user) {
    const float4 c4 = *(const float4*)(w_uui + E_DIM + j * 4);
    dC = halfSum(v.x * c4.x + v.y * c4.y + v.z * c4.z + v.w * c4.w);
  }
  if (j == 0) {
    if (is_user) {
      user_s[r] = s;
      pU0[r] = dA;
      pU1[r] = dB;
      pU2[r] = dC;
    } else {
      item_s[r] = s;
      pI1[r] = dA;
      pI2[r] = dB;
    }
  }
}

// One wave per (b, k). Logits from fp32 row projections. Weighted sum:
// EIGHTH-WAVE uint4 row loads — each 8-lane eighth loads one full 128B
// int8 row per instruction, so one wave instruction covers 8 rows and the
// L=64 gather runs in 8 latency windows (was 16). Per-row dequant scales
// folded into the broadcast weight. Depth-1 rolling prefetch, no arrays
// (R8/R10 lessons). NO global atomics (R14/R16 lessons).
__global__ __launch_bounds__(256) void phase1_i8(
    const float* __restrict__ user_embs,  // fp32 (self rows)
    const signed char* __restrict__ user_q,
    const signed char* __restrict__ item_q,
    const float* __restrict__ user_s, const float* __restrict__ item_s,
    const float* __restrict__ projU0, const float* __restrict__ projU1,
    const float* __restrict__ projU2, const float* __restrict__ projI1,
    const float* __restrict__ projI2,
    const float* __restrict__ w_uu, const float* __restrict__ w_uiu,
    const float* __restrict__ w_uui, const float* __restrict__ W0,
    const float* __restrict__ b0, const float* __restrict__ w1,
    const int* __restrict__ uid, const int* __restrict__ nbr,
    const int* __restrict__ uiu, const int* __restrict__ uui,
    float* __restrict__ feats,     // [3][B][E]
    float* __restrict__ partials,  // [3][B]
    int B) {
  const int lane = threadIdx.x & 63;
  const int j = lane & 7;        // dim chunk: dims 16j..16j+15
  const int eighth = lane >> 3;  // 0..7: which row of an 8-row group
  const int wv = threadIdx.x >> 6;
  const int w_id = blockIdx.x * 4 + wv;
  const int b = w_id / 3;
  const int k = w_id - 3 * b;
  if (b >= B) return;  // grid exact for B%4==0

  __shared__ float sc[4][E_DIM];

  const int u = uid[b];
  const float2 self2 = *(const float2*)(user_embs + (long)u * E_DIM + lane * 2);

  const float* w = (k == 0) ? w_uu : (k == 1) ? w_uiu : w_uui;
  const float2 wa = *(const float2*)(w + lane * 2);
  const float2 wb = *(const float2*)(w + E_DIM + lane * 2);
  const float S1 = waveSum(self2.x * wa.x + self2.y * wa.y);
  const float S2 = waveSum(self2.x * wb.x + self2.y * wb.y);

  const bool is_uu = (k == 0);
  const float scale = is_uu ? 0.5f : (1.0f / 3.0f);
  // tables: k==0 -> user; k==1 (uiu) -> item,user; k==2 (uui) -> user,item
  const uint4* T0 = (const uint4*)((k == 1) ? item_q : user_q);
  const uint4* T1 = (const uint4*)((k == 1) ? user_q : item_q);
  const float* S0t = (k == 1) ? item_s : user_s;
  const float* S1t = (k == 1) ? user_s : item_s;
  const float* p0 = (k == 0) ? projU0 : (k == 1) ? projI1 : projU2;
  const float* p1 = (k == 1) ? projU1 : projI2;  // unused for k==0

  // lane l owns neighbor l's indices (coalesced)
  int i0_l, i1_l;
  if (is_uu) {
    i0_l = nbr[b * L_DIM + lane];
    i1_l = 0;
  } else {
    const int* mp = (k == 1) ? uiu : uui;
    i0_l = mp[(b * 2 + 0) * L_DIM + lane];
    i1_l = mp[(b * 2 + 1) * L_DIM + lane];
  }

  // ---- logits from projections ----
  float d = p0[i0_l];
  if (!is_uu) d += p1[i1_l];
  float logit = S1 + scale * (S2 + d);
  logit = (logit > 0.f) ? logit : 0.01f * logit;  // leaky_relu
  if (i0_l == 0) logit += -100000000.0f;          // mask

  const float M = waveMax(logit);
  const float p = __expf(logit - M);
  const float Z = waveSum(p);
  const float a_l = p / Z;  // lane l: neighbor l's attention weight

  // fold per-row dequant scales into the weights (lane = neighbor)
  const float as0_l = a_l * S0t[i0_l];
  const float as1_l = is_uu ? 0.f : a_l * S1t[i1_l];

  // ---- weighted sum: 8 rows/instruction (eighth-wave uint4), depth-1 --
  constexpr int RQ = E_DIM / 16;  // 8 uint4 per 128B int8 row
  float o0 = 0.f, o1 = 0.f, o2 = 0.f, o3 = 0.f;
  float o4 = 0.f, o5 = 0.f, o6 = 0.f, o7 = 0.f;
  float o8 = 0.f, o9 = 0.f, o10 = 0.f, o11 = 0.f;
  float o12 = 0.f, o13 = 0.f, o14 = 0.f, o15 = 0.f;

  int l8 = eighth;
  float a0c = __shfl(as0_l, l8);
  float a1c = 0.f;
  int i0 = __shfl(i0_l, l8);
  uint4 q0 = T0[(long)i0 * RQ + j];
  uint4 q1 = make_uint4(0, 0, 0, 0);
  if (!is_uu) {
    a1c = __shfl(as1_l, l8);
    const int i1 = __shfl(i1_l, l8);
    q1 = T1[(long)i1 * RQ + j];
  }

  for (int it = 0; it < L_DIM / 8; ++it) {
    const float a0 = a0c, a1 = a1c;
    const uint4 qa = q0, qb = q1;
    if (it < L_DIM / 8 - 1) {  // prefetch next 8-row group
      l8 = 8 * (it + 1) + eighth;
      a0c = __shfl(as0_l, l8);
      i0 = __shfl(i0_l, l8);
      q0 = T0[(long)i0 * RQ + j];
      if (!is_uu) {
        a1c = __shfl(as1_l, l8);
        const int i1 = __shfl(i1_l, l8);
        q1 = T1[(long)i1 * RQ + j];
      }
    }
    // dims 16j+0..3 from qa.x, +4..7 qa.y, +8..11 qa.z, +12..15 qa.w
    o0 += a0 * (float)(signed char)(qa.x);
    o1 += a0 * (float)(signed char)(qa.x >> 8);
    o2 += a0 * (float)(signed char)(qa.x >> 16);
    o3 += a0 * (float)((int)qa.x >> 24);
    o4 += a0 * (float)(signed char)(qa.y);
    o5 += a0 * (float)(signed char)(qa.y >> 8);
    o6 += a0 * (float)(signed char)(qa.y >> 16);
    o7 += a0 * (float)((int)qa.y >> 24);
    o8 += a0 * (float)(signed char)(qa.z);
    o9 += a0 * (float)(signed char)(qa.z >> 8);
    o10 += a0 * (float)(signed char)(qa.z >> 16);
    o11 += a0 * (float)((int)qa.z >> 24);
    o12 += a0 * (float)(signed char)(qa.w);
    o13 += a0 * (float)(signed char)(qa.w >> 8);
    o14 += a0 * (float)(signed char)(qa.w >> 16);
    o15 += a0 * (float)((int)qa.w >> 24);
    if (!is_uu) {
      o0 += a1 * (float)(signed char)(qb.x);
      o1 += a1 * (float)(signed char)(qb.x >> 8);
      o2 += a1 * (float)(signed char)(qb.x >> 16);
      o3 += a1 * (float)((int)qb.x >> 24);
      o4 += a1 * (float)(signed char)(qb.y);
      o5 += a1 * (float)(signed char)(qb.y >> 8);
      o6 += a1 * (float)(signed char)(qb.y >> 16);
      o7 += a1 * (float)((int)qb.y >> 24);
      o8 += a1 * (float)(signed char)(qb.z);
      o9 += a1 * (float)(signed char)(qb.z >> 8);
      o10 += a1 * (float)(signed char)(qb.z >> 16);
      o11 += a1 * (float)((int)qb.z >> 24);
      o12 += a1 * (float)(signed char)(qb.w);
      o13 += a1 * (float)(signed char)(qb.w >> 8);
      o14 += a1 * (float)(signed char)(qb.w >> 16);
      o15 += a1 * (float)((int)qb.w >> 24);
    }
  }
  // combine the 8 eighths (each summed 8 of the 64 neighbors)
  o0 += __shfl_xor(o0, 8); o0 += __shfl_xor(o0, 16); o0 += __shfl_xor(o0, 32);
  o1 += __shfl_xor(o1, 8); o1 += __shfl_xor(o1, 16); o1 += __shfl_xor(o1, 32);
  o2 += __shfl_xor(o2, 8); o2 += __shfl_xor(o2, 16); o2 += __shfl_xor(o2, 32);
  o3 += __shfl_xor(o3, 8); o3 += __shfl_xor(o3, 16); o3 += __shfl_xor(o3, 32);
  o4 += __shfl_xor(o4, 8); o4 += __shfl_xor(o4, 16); o4 += __shfl_xor(o4, 32);
  o5 += __shfl_xor(o5, 8); o5 += __shfl_xor(o5, 16); o5 += __shfl_xor(o5, 32);
  o6 += __shfl_xor(o6, 8); o6 += __shfl_xor(o6, 16); o6 += __shfl_xor(o6, 32);
  o7 += __shfl_xor(o7, 8); o7 += __shfl_xor(o7, 16); o7 += __shfl_xor(o7, 32);
  o8 += __shfl_xor(o8, 8); o8 += __shfl_xor(o8, 16); o8 += __shfl_xor(o8, 32);
  o9 += __shfl_xor(o9, 8); o9 += __shfl_xor(o9, 16); o9 += __shfl_xor(o9, 32);
  o10 += __shfl_xor(o10, 8); o10 += __shfl_xor(o10, 16); o10 += __shfl_xor(o10, 32);
  o11 += __shfl_xor(o11, 8); o11 += __shfl_xor(o11, 16); o11 += __shfl_xor(o11, 32);
  o12 += __shfl_xor(o12, 8); o12 += __shfl_xor(o12, 16); o12 += __shfl_xor(o12, 32);
  o13 += __shfl_xor(o13, 8); o13 += __shfl_xor(o13, 16); o13 += __shfl_xor(o13, 32);
  o14 += __shfl_xor(o14, 8); o14 += __shfl_xor(o14, 16); o14 += __shfl_xor(o14, 32);
  o15 += __shfl_xor(o15, 8); o15 += __shfl_xor(o15, 16); o15 += __shfl_xor(o15, 32);

  // sum_l a_l = 1  =>  out = scale * (self + sum as0*q0 [+ as1*q1])
  const long sbase = (long)u * E_DIM + j * 16;
  const float4 sA = *(const float4*)(user_embs + sbase);
  const float4 sB = *(const float4*)(user_embs + sbase + 4);
  const float4 sC = *(const float4*)(user_embs + sbase + 8);
  const float4 sD = *(const float4*)(user_embs + sbase + 12);
  float4 rA, rB, rC, rD;
  rA.x = fmaxf((sA.x + o0) * scale, 0.f);
  rA.y = fmaxf((sA.y + o1) * scale, 0.f);
  rA.z = fmaxf((sA.z + o2) * scale, 0.f);
  rA.w = fmaxf((sA.w + o3) * scale, 0.f);
  rB.x = fmaxf((sB.x + o4) * scale, 0.f);
  rB.y = fmaxf((sB.y + o5) * scale, 0.f);
  rB.z = fmaxf((sB.z + o6) * scale, 0.f);
  rB.w = fmaxf((sB.w + o7) * scale, 0.f);
  rC.x = fmaxf((sC.x + o8) * scale, 0.f);
  rC.y = fmaxf((sC.y + o9) * scale, 0.f);
  rC.z = fmaxf((sC.z + o10) * scale, 0.f);
  rC.w = fmaxf((sC.w + o11) * scale, 0.f);
  rD.x = fmaxf((sD.x + o12) * scale, 0.f);
  rD.y = fmaxf((sD.y + o13) * scale, 0.f);
  rD.z = fmaxf((sD.z + o14) * scale, 0.f);
  rD.w = fmaxf((sD.w + o15) * scale, 0.f);
  if (lane < 8) {  // 8 lanes x 16 dims = full 128-dim row
    float* fp = feats + ((long)k * B + b) * E_DIM + j * 16;
    *(float4*)fp = rA;
    *(float4*)(fp + 4) = rB;
    *(float4*)(fp + 8) = rC;
    *(float4*)(fp + 12) = rD;
    *(float4*)(&sc[wv][j * 16]) = rA;
    *(float4*)(&sc[wv][j * 16 + 4]) = rB;
    *(float4*)(&sc[wv][j * 16 + 8]) = rC;
    *(float4*)(&sc[wv][j * 16 + 12]) = rD;
  }
  __syncthreads();

  // ---- inter(): hid[j] = b0[j] + sum_e r[e] * W0[e][j] ----
  float hid = b0[lane];
#pragma unroll 4
  for (int e = 0; e < E_DIM; ++e) hid += sc[wv][e] * W0[e * HDIM + lane];
  const float pp = tanhf(hid) * w1[lane];
  const float sum = waveSum(pp);
  if (lane == 0) partials[(long)k * B + b] = sum;
}

// Fallback (proven R4 kernel): fp32 gathers, used only if ws is too small.
__global__ __launch_bounds__(256) void phase1_f32(
    const float* __restrict__ user_embs, const float* __restrict__ item_embs,
    const float* __restrict__ w_uu, const float* __restrict__ w_uiu,
    const float* __restrict__ w_uui, const float* __restrict__ W0,
    const float* __restrict__ b0, const float* __restrict__ w1,
    const int* __restrict__ uid, const int* __restrict__ nbr,
    const int* __restrict__ uiu, const int* __restrict__ uui,
    float* __restrict__ feats, float* __restrict__ partials, int B) {
  const int lane = threadIdx.x & 63;
  const int wv = threadIdx.x >> 6;
  const int w_id = blockIdx.x * 4 + wv;
  const int b = w_id / 3;
  const int k = w_id - 3 * b;
  if (b >= B) return;

  __shared__ float sc[4][E_DIM];
  const int u = uid[b];
  const float self0 = user_embs[u * E_DIM + lane];
  const float self1 = user_embs[u * E_DIM + 64 + lane];
  const float* w = (k == 0) ? w_uu : (k == 1) ? w_uiu : w_uui;
  const float wa0 = w[lane], wa1 = w[64 + lane];
  const float wb0 = w[128 + lane], wb1 = w[192 + lane];
  const float logit_self = waveSum(self0 * wa0 + self1 * wa1);
  const bool is_uu = (k == 0);
  const float scale = is_uu ? 0.5f : (1.0f / 3.0f);
  const float* t0 = (k == 1) ? item_embs : user_embs;
  const float* t1 = (k == 1) ? user_embs : item_embs;
  int i0_l, i1_l;
  if (is_uu) {
    i0_l = nbr[b * L_DIM + lane];
    i1_l = 0;
  } else {
    const int* mp = (k == 1) ? uiu : uui;
    i0_l = mp[(b * 2 + 0) * L_DIM + lane];
    i1_l = mp[(b * 2 + 1) * L_DIM + lane];
  }
  const float mask_l = (i0_l == 0) ? 1.0f : 0.0f;
  float m = -3.0e38f, s = 0.0f, o0 = 0.0f, o1 = 0.0f;
  int i0 = __shfl(i0_l, 0), i1 = __shfl(i1_l, 0);
  float g00 = t0[i0 * E_DIM + lane];
  float g01 = t0[i0 * E_DIM + 64 + lane];
  float g10 = 0.f, g11 = 0.f;
  if (!is_uu) {
    g10 = t1[i1 * E_DIM + lane];
    g11 = t1[i1 * E_DIM + 64 + lane];
  }
  for (int l = 0; l < L_DIM; ++l) {
    const float f0 = (self0 + g00 + g10) * scale;
    const float f1 = (self1 + g01 + g11) * scale;
    if (l < L_DIM - 1) {
      i0 = __shfl(i0_l, l + 1);
      i1 = __shfl(i1_l, l + 1);
      g00 = t0[i0 * E_DIM + lane];
      g01 = t0[i0 * E_DIM + 64 + lane];
      if (!is_uu) {
        g10 = t1[i1 * E_DIM + lane];
        g11 = t1[i1 * E_DIM + 64 + lane];
      }
    }
    float logit = waveSum(f0 * wb0 + f1 * wb1) + logit_self;
    logit = (logit > 0.f) ? logit : 0.01f * logit;
    logit += -100000000.0f * __shfl(mask_l, l);
    const float mn = fmaxf(m, logit);
    const float alpha = __expf(m - mn);
    const float p = __expf(logit - mn);
    s = s * alpha + p;
    o0 = o0 * alpha + p * f0;
    o1 = o1 * alpha + p * f1;
    m = mn;
  }
  const float inv_s = 1.0f / s;
  const float r0 = fmaxf(o0 * inv_s, 0.f);
  const float r1 = fmaxf(o1 * inv_s, 0.f);
  feats[((long)k * B + b) * E_DIM + lane] = r0;
  feats[((long)k * B + b) * E_DIM + 64 + lane] = r1;
  sc[wv][lane] = r0;
  sc[wv][64 + lane] = r1;
  __syncthreads();
  float hid = b0[lane];
#pragma unroll 4
  for (int e = 0; e < E_DIM; ++e) hid += sc[wv][e] * W0[e * HDIM + lane];
  const float p = tanhf(hid) * w1[lane];
  const float sum = waveSum(p);
  if (lane == 0) partials[(long)k * B + b] = sum;
}

__global__ __launch_bounds__(256) void reduce_scores(
    const float* __restrict__ partials, float* __restrict__ weights, int B) {
  __shared__ float red[256];
  const int tid = threadIdx.x;
  float s[3];
#pragma unroll
  for (int k = 0; k < 3; ++k) {
    float acc = 0.f;
    for (int i = tid; i < B; i += 256) acc += partials[(long)k * B + i];
    red[tid] = acc;
    __syncthreads();
    for (int off = 128; off > 0; off >>= 1) {
      if (tid < off) red[tid] += red[tid + off];
      __syncthreads();
    }
    s[k] = red[0];
    __syncthreads();
  }
  if (tid == 0) {
    const float inv_b = 1.0f / (float)B;
    const float s0 = s[0] * inv_b, s1 = s[1] * inv_b, s2 = s[2] * inv_b;
    const float m = fmaxf(s0, fmaxf(s1, s2));
    const float e0 = __expf(s0 - m);
    const float e1 = __expf(s1 - m);
    const float e2 = __expf(s2 - m);
    const float inv = 1.0f / (e0 + e1 + e2);
    weights[0] = e0 * inv;
    weights[1] = e1 * inv;
    weights[2] = e2 * inv;
  }
}

__global__ __launch_bounds__(256) void phase2(
    const float* __restrict__ feats, const float* __restrict__ weights,
    float* __restrict__ out, int B) {
  const int i = blockIdx.x * blockDim.x + threadIdx.x;
  const int n = B * E_DIM;
  if (i >= n) return;
  const float w0 = weights[0], w1 = weights[1], w2 = weights[2];
  const float v = w0 * feats[i] + w1 * feats[n + i] + w2 * feats[2 * n + i];
  out[i] = fmaxf(v, 0.f);
}

// Main-path phase2 (proven R2): every block REDUNDANTLY reduces
// partials[3][B] (48 KB, L2/L3-resident) -> block-local 3-way softmax ->
// grid-stride weighted combine. Zero inter-block communication.
__global__ __launch_bounds__(256) void phase2_fused(
    const float* __restrict__ partials, const float* __restrict__ feats,
    float* __restrict__ out, int B) {
  __shared__ float red[3][4];
  const int tid = threadIdx.x;
  const int lane = tid & 63;
  const int wv = tid >> 6;

  float s0 = 0.f, s1 = 0.f, s2 = 0.f;
  if ((B & 3) == 0) {
    const float4* p4 = (const float4*)partials;
    const int nb4 = B >> 2;
    for (int i = tid; i < nb4; i += 256) {
      const float4 v0 = p4[i];
      const float4 v1 = p4[nb4 + i];
      const float4 v2 = p4[2 * nb4 + i];
      s0 += (v0.x + v0.y) + (v0.z + v0.w);
      s1 += (v1.x + v1.y) + (v1.z + v1.w);
      s2 += (v2.x + v2.y) + (v2.z + v2.w);
    }
  } else {
    for (int i = tid; i < B; i += 256) {
      s0 += partials[i];
      s1 += partials[B + i];
      s2 += partials[2 * B + i];
    }
  }
  s0 = waveSum(s0);
  s1 = waveSum(s1);
  s2 = waveSum(s2);
  if (lane == 0) {
    red[0][wv] = s0;
    red[1][wv] = s1;
    red[2][wv] = s2;
  }
  __syncthreads();
  const float inv_b = 1.0f / (float)B;
  const float a0 = (red[0][0] + red[0][1] + red[0][2] + red[0][3]) * inv_b;
  const float a1 = (red[1][0] + red[1][1] + red[1][2] + red[1][3]) * inv_b;
  const float a2 = (red[2][0] + red[2][1] + red[2][2] + red[2][3]) * inv_b;
  const float m = fmaxf(a0, fmaxf(a1, a2));
  const float e0 = __expf(a0 - m);
  const float e1 = __expf(a1 - m);
  const float e2 = __expf(a2 - m);
  const float inv = 1.0f / (e0 + e1 + e2);
  const float w0 = e0 * inv, w1 = e1 * inv, w2 = e2 * inv;

  const int n4 = (B * E_DIM) >> 2;
  const float4* f4 = (const float4*)feats;
  float4* o4 = (float4*)out;
  for (int i = blockIdx.x * 256 + tid; i < n4; i += gridDim.x * 256) {
    const float4 x = f4[i];
    const float4 y = f4[n4 + i];
    const float4 z = f4[2 * n4 + i];
    float4 r;
    r.x = fmaxf(w0 * x.x + w1 * y.x + w2 * z.x, 0.f);
    r.y = fmaxf(w0 * x.y + w1 * y.y + w2 * z.y, 0.f);
    r.z = fmaxf(w0 * x.z + w1 * y.z + w2 * z.z, 0.f);
    r.w = fmaxf(w0 * x.w + w1 * y.w + w2 * z.w, 0.f);
    o4[i] = r;
  }
}

extern "C" void kernel_launch(void* const* d_in, const int* in_sizes, int n_in,
                              void* d_out, int out_size, void* d_ws,
                              size_t ws_size, hipStream_t stream) {
  const float* user_embs = (const float*)d_in[0];
  const float* item_embs = (const float*)d_in[1];
  const float* w_uu = (const float*)d_in[2];
  const float* w_uiu = (const float*)d_in[3];
  const float* w_uui = (const float*)d_in[4];
  const float* W0 = (const float*)d_in[5];
  const float* b0 = (const float*)d_in[6];
  const float* w1 = (const float*)d_in[7];
  const int* uid = (const int*)d_in[8];
  const int* nbr = (const int*)d_in[9];
  const int* uiu = (const int*)d_in[10];
  const int* uui = (const int*)d_in[11];
  const int B = in_sizes[8];
  const int nU = in_sizes[0];  // user table elems
  const int nI = in_sizes[1];  // item table elems
  const int nUr = nU / E_DIM;  // user rows
  const int nIr = nI / E_DIM;  // item rows

  float* ws = (float*)d_ws;
  float* partials = ws;            // [3][B]
  float* weights = ws + 3 * B;     // [3] (+pad) — fallback path only
  float* feats = ws + 3 * B + 64;  // [3][B][E]
  const size_t f32_floats = (size_t)3 * B + 64 + (size_t)3 * B * E_DIM;
  // int8 tables (1 B/elem), then per-row scales, then projections
  signed char* user_q = (signed char*)(ws + f32_floats);
  signed char* item_q = user_q + nU;
  const size_t qwords = ((size_t)nU + nI + 3) / 4;  // table bytes in floats
  float* user_s = ws + f32_floats + qwords;
  float* item_s = user_s + nUr;
  float* projU0 = item_s + nIr;
  float* projU1 = projU0 + nUr;
  float* projU2 = projU1 + nUr;
  float* projI1 = projU2 + nUr;
  float* projI2 = projI1 + nIr;
  const size_t need =
      (f32_floats + qwords + (size_t)(nUr + nIr) + (size_t)3 * nUr +
       (size_t)2 * nIr) *
      4;

  const int n_waves = 3 * B;
  const int n_blocks = (n_waves + 3) / 4;
  const int n = B * E_DIM;

  if (ws_size >= need) {
    const int conv_waves = (nUr + nIr + 1) / 2;  // 2 rows per wave
    convert_i8<<<(conv_waves + 3) / 4, 256, 0, stream>>>(
        user_embs, item_embs, user_q, item_q, user_s, item_s, w_uu, w_uiu,
        w_uui, projU0, projU1, projU2, projI1, projI2, nUr, nIr);
    phase1_i8<<<n_blocks, 256, 0, stream>>>(
        user_embs, user_q, item_q, user_s, item_s, projU0, projU1, projU2,
        projI1, projI2, w_uu, w_uiu, w_uui, W0, b0, w1, uid, nbr, uiu, uui,
        feats, partials, B);
    phase2_fused<<<256, 256, 0, stream>>>(partials, feats, (float*)d_out, B);
  } else {
    phase1_f32<<<n_blocks, 256, 0, stream>>>(user_embs, item_embs, w_uu,
                                             w_uiu, w_uui, W0, b0, w1, uid,
                                             nbr, uiu, uui, feats, partials, B);
    reduce_scores<<<1, 256, 0, stream>>>(partials, weights, B);
    phase2<<<(n + 255) / 256, 256, 0, stream>>>(feats, weights, (float*)d_out,
                                                B);
  }
}

// Round 6
// 184.998 us; speedup vs baseline: 1.0217x; 1.0217x over previous
//
#include <hip/hip_runtime.h>

#define E_DIM 128
#define L_DIM 64
#define HDIM 64

__device__ __forceinline__ float waveSum(float v) {
#pragma unroll
  for (int o = 32; o > 0; o >>= 1) v += __shfl_xor(v, o);
  return v;
}
__device__ __forceinline__ float waveMax(float v) {
#pragma unroll
  for (int o = 32; o > 0; o >>= 1) v = fmaxf(v, __shfl_xor(v, o));
  return v;
}
__device__ __forceinline__ float halfSum(float v) {  // reduce within 32 lanes
#pragma unroll
  for (int o = 16; o > 0; o >>= 1) v += __shfl_xor(v, o);
  return v;
}
__device__ __forceinline__ float halfMax(float v) {  // max within 32 lanes
#pragma unroll
  for (int o = 16; o > 0; o >>= 1) v = fmaxf(v, __shfl_xor(v, o));
  return v;
}

// ---------------------------------------------------------------------------
// R19. Ledger: R14 contended global atomics = +23 µs. R16 coop grid.sync =
// 2x worse (device-scope spin-storm). R17 int8 rows = 69.5->58 µs. R18
// 8-row/eighth-wave = NEUTRAL (window-count model falsified: instr count
// halved, time flat) -> binding constraint is TOTAL random cache-line
// touches serviced at a line rate, not windows or instructions.
// R19 change: the ignored SCALAR gathers are 2/3 of the line budget for
// k!=0 waves: p0[i0]+p1[i1]+S0[i0]+S1[i1] = 256 random line-touches vs
// 128 for the row gather itself (scale gathers were ADDED by int8 in R17).
// Merge {proj, scale} into one float2 record per (table,branch): one 8B
// load serves logit AND dequant scale -> 256->128 / 128->64 scalar
// touches. Also revert to R17's proven quarter-wave uint2 gather shape
// (VGPR 28, occ 67%, fewer ds_bpermute than R18).
// ---------------------------------------------------------------------------

// Convert pass: half-wave h handles global row 2*gw+h; user rows first,
// then item rows. Lane j covers dims 4j..4j+3. Row max via halfMax
// butterfly; int8 quantize + pack 4/lane; projections from fp32 values;
// {proj, scale} written as float2 pairs (qU0/qU1/qU2 user, qI1/qI2 item).
__global__ __launch_bounds__(256) void convert_i8(
    const float* __restrict__ user_src, const float* __restrict__ item_src,
    signed char* __restrict__ user_q, signed char* __restrict__ item_q,
    const float* __restrict__ w_uu, const float* __restrict__ w_uiu,
    const float* __restrict__ w_uui, float2* __restrict__ qU0,
    float2* __restrict__ qU1, float2* __restrict__ qU2,
    float2* __restrict__ qI1, float2* __restrict__ qI2, int nUr, int nIr) {
  const int lane = threadIdx.x & 63;
  const int j = lane & 31;
  const int h = lane >> 5;
  const int gw = blockIdx.x * 4 + (threadIdx.x >> 6);
  const int r_all = gw * 2 + h;
  if (r_all >= nUr + nIr) return;

  const bool is_user = (r_all < nUr);
  const int r = is_user ? r_all : r_all - nUr;
  const float* src = is_user ? user_src : item_src;
  signed char* dst = is_user ? user_q : item_q;

  const float4 v = *(const float4*)(src + (long)r * E_DIM + j * 4);

  // ---- per-row absmax -> scale ----
  float am =
      fmaxf(fmaxf(fabsf(v.x), fabsf(v.y)), fmaxf(fabsf(v.z), fabsf(v.w)));
  am = halfMax(am);
  const float s = am * (1.0f / 127.0f);
  const float inv = (am > 0.f) ? 127.0f / am : 0.f;

  int q0 = __float2int_rn(v.x * inv);
  int q1 = __float2int_rn(v.y * inv);
  int q2 = __float2int_rn(v.z * inv);
  int q3 = __float2int_rn(v.w * inv);
  q0 = max(-127, min(127, q0));
  q1 = max(-127, min(127, q1));
  q2 = max(-127, min(127, q2));
  q3 = max(-127, min(127, q3));
  const unsigned int pk = (unsigned int)(q0 & 255) |
                          ((unsigned int)(q1 & 255) << 8) |
                          ((unsigned int)(q2 & 255) << 16) |
                          ((unsigned int)(q3 & 255) << 24);
  ((unsigned int*)dst)[(long)r * (E_DIM / 4) + j] = pk;

  // ---- projections from ORIGINAL fp32 values (reference-consistent) ----
  const float* wA = is_user ? w_uu : w_uiu;
  const float* wB = is_user ? w_uiu : w_uui;
  const float4 a4 = *(const float4*)(wA + E_DIM + j * 4);
  const float dA = halfSum(v.x * a4.x + v.y * a4.y + v.z * a4.z + v.w * a4.w);
  const float4 b4 = *(const float4*)(wB + E_DIM + j * 4);
  const float dB = halfSum(v.x * b4.x + v.y * b4.y + v.z * b4.z + v.w * b4.w);
  float dC = 0.f;
  if (is_user) {
    const float4 c4 = *(const float4*)(w_uui + E_DIM + j * 4);
    dC = halfSum(v.x * c4.x + v.y * c4.y + v.z * c4.z + v.w * c4.w);
  }
  if (j == 0) {
    if (is_user) {
      qU0[r] = make_float2(dA, s);
      qU1[r] = make_float2(dB, s);
      qU2[r] = make_float2(dC, s);
    } else {
      qI1[r] = make_float2(dA, s);
      qI2[r] = make_float2(dB, s);
    }
  }
}

// One wave per (b, k). Logits+scales from ONE float2 gather per table
// (was 2 separate 4B gathers -> halves the dominant scalar line-touch
// budget). Weighted sum: QUARTER-WAVE uint2 row loads (proven R17 shape:
// 16-lane quarter loads one 128B int8 row per instruction). Per-row
// dequant scales folded into the broadcast weight. Depth-1 rolling
// prefetch, no arrays. NO global atomics (R14/R16 lessons).
__global__ __launch_bounds__(256) void phase1_i8(
    const float* __restrict__ user_embs,  // fp32 (self rows)
    const signed char* __restrict__ user_q,
    const signed char* __restrict__ item_q,
    const float2* __restrict__ qU0, const float2* __restrict__ qU1,
    const float2* __restrict__ qU2, const float2* __restrict__ qI1,
    const float2* __restrict__ qI2,
    const float* __restrict__ w_uu, const float* __restrict__ w_uiu,
    const float* __restrict__ w_uui, const float* __restrict__ W0,
    const float* __restrict__ b0, const float* __restrict__ w1,
    const int* __restrict__ uid, const int* __restrict__ nbr,
    const int* __restrict__ uiu, const int* __restrict__ uui,
    float* __restrict__ feats,     // [3][B][E]
    float* __restrict__ partials,  // [3][B]
    int B) {
  const int lane = threadIdx.x & 63;
  const int j = lane & 15;        // dim chunk: dims 8j..8j+7
  const int quarter = lane >> 4;  // 0..3: which row of a 4-row group
  const int wv = threadIdx.x >> 6;
  const int w_id = blockIdx.x * 4 + wv;
  const int b = w_id / 3;
  const int k = w_id - 3 * b;
  if (b >= B) return;  // grid exact for B%4==0

  __shared__ float sc[4][E_DIM];

  const bool is_uu = (k == 0);
  const float scale = is_uu ? 0.5f : (1.0f / 3.0f);
  // tables: k==0 -> user; k==1 (uiu) -> item,user; k==2 (uui) -> user,item
  const uint2* T0 = (const uint2*)((k == 1) ? item_q : user_q);
  const uint2* T1 = (const uint2*)((k == 1) ? user_q : item_q);
  const float2* P0 = (k == 0) ? qU0 : (k == 1) ? qI1 : qU2;
  const float2* P1 = (k == 1) ? qU1 : qI2;  // unused for k==0

  // ---- issue index + {proj,scale} gathers FIRST (latency hides under
  //      the self-projection butterflies below) ----
  int i0_l, i1_l;
  if (is_uu) {
    i0_l = nbr[b * L_DIM + lane];
    i1_l = 0;
  } else {
    const int* mp = (k == 1) ? uiu : uui;
    i0_l = mp[(b * 2 + 0) * L_DIM + lane];
    i1_l = mp[(b * 2 + 1) * L_DIM + lane];
  }
  const float2 ps0 = P0[i0_l];  // {proj, dequant scale}
  float2 ps1 = make_float2(0.f, 0.f);
  if (!is_uu) ps1 = P1[i1_l];

  const int u = uid[b];
  const float2 self2 = *(const float2*)(user_embs + (long)u * E_DIM + lane * 2);

  const float* w = (k == 0) ? w_uu : (k == 1) ? w_uiu : w_uui;
  const float2 wa = *(const float2*)(w + lane * 2);
  const float2 wb = *(const float2*)(w + E_DIM + lane * 2);
  const float S1 = waveSum(self2.x * wa.x + self2.y * wa.y);
  const float S2 = waveSum(self2.x * wb.x + self2.y * wb.y);

  // ---- logits from projections ----
  float d = ps0.x;
  if (!is_uu) d += ps1.x;
  float logit = S1 + scale * (S2 + d);
  logit = (logit > 0.f) ? logit : 0.01f * logit;  // leaky_relu
  if (i0_l == 0) logit += -100000000.0f;          // mask

  const float M = waveMax(logit);
  const float p = __expf(logit - M);
  const float Z = waveSum(p);
  const float a_l = p / Z;  // lane l: neighbor l's attention weight

  // fold per-row dequant scales into the weights (lane = neighbor)
  const float as0_l = a_l * ps0.y;
  const float as1_l = is_uu ? 0.f : a_l * ps1.y;

  // ---- weighted sum: 4 rows/instruction (quarter-wave uint2), depth-1 --
  constexpr int RQ = E_DIM / 8;  // 16 uint2 per 128B int8 row
  float o0 = 0.f, o1 = 0.f, o2 = 0.f, o3 = 0.f;
  float o4 = 0.f, o5 = 0.f, o6 = 0.f, o7 = 0.f;

  int l4 = quarter;
  float a0c = __shfl(as0_l, l4);
  float a1c = 0.f;
  int i0 = __shfl(i0_l, l4);
  uint2 q0 = T0[(long)i0 * RQ + j];
  uint2 q1 = make_uint2(0, 0);
  if (!is_uu) {
    a1c = __shfl(as1_l, l4);
    const int i1 = __shfl(i1_l, l4);
    q1 = T1[(long)i1 * RQ + j];
  }

  for (int it = 0; it < L_DIM / 4; ++it) {
    const float a0 = a0c, a1 = a1c;
    const uint2 qa = q0, qb = q1;
    if (it < L_DIM / 4 - 1) {  // prefetch next 4-row group
      l4 = 4 * (it + 1) + quarter;
      a0c = __shfl(as0_l, l4);
      i0 = __shfl(i0_l, l4);
      q0 = T0[(long)i0 * RQ + j];
      if (!is_uu) {
        a1c = __shfl(as1_l, l4);
        const int i1 = __shfl(i1_l, l4);
        q1 = T1[(long)i1 * RQ + j];
      }
    }
    // dims 8j..8j+3 from qa.x bytes, 8j+4..8j+7 from qa.y bytes
    o0 += a0 * (float)(signed char)(qa.x);
    o1 += a0 * (float)(signed char)(qa.x >> 8);
    o2 += a0 * (float)(signed char)(qa.x >> 16);
    o3 += a0 * (float)((int)qa.x >> 24);
    o4 += a0 * (float)(signed char)(qa.y);
    o5 += a0 * (float)(signed char)(qa.y >> 8);
    o6 += a0 * (float)(signed char)(qa.y >> 16);
    o7 += a0 * (float)((int)qa.y >> 24);
    if (!is_uu) {
      o0 += a1 * (float)(signed char)(qb.x);
      o1 += a1 * (float)(signed char)(qb.x >> 8);
      o2 += a1 * (float)(signed char)(qb.x >> 16);
      o3 += a1 * (float)((int)qb.x >> 24);
      o4 += a1 * (float)(signed char)(qb.y);
      o5 += a1 * (float)(signed char)(qb.y >> 8);
      o6 += a1 * (float)(signed char)(qb.y >> 16);
      o7 += a1 * (float)((int)qb.y >> 24);
    }
  }
  // combine the 4 quarters (each summed 16 of the 64 neighbors)
  o0 += __shfl_xor(o0, 16); o0 += __shfl_xor(o0, 32);
  o1 += __shfl_xor(o1, 16); o1 += __shfl_xor(o1, 32);
  o2 += __shfl_xor(o2, 16); o2 += __shfl_xor(o2, 32);
  o3 += __shfl_xor(o3, 16); o3 += __shfl_xor(o3, 32);
  o4 += __shfl_xor(o4, 16); o4 += __shfl_xor(o4, 32);
  o5 += __shfl_xor(o5, 16); o5 += __shfl_xor(o5, 32);
  o6 += __shfl_xor(o6, 16); o6 += __shfl_xor(o6, 32);
  o7 += __shfl_xor(o7, 16); o7 += __shfl_xor(o7, 32);

  // sum_l a_l = 1  =>  out = scale * (self + sum as0*q0 [+ as1*q1])
  const float4 sA = *(const float4*)(user_embs + (long)u * E_DIM + j * 8);
  const float4 sB = *(const float4*)(user_embs + (long)u * E_DIM + j * 8 + 4);
  float4 rA, rB;
  rA.x = fmaxf((sA.x + o0) * scale, 0.f);
  rA.y = fmaxf((sA.y + o1) * scale, 0.f);
  rA.z = fmaxf((sA.z + o2) * scale, 0.f);
  rA.w = fmaxf((sA.w + o3) * scale, 0.f);
  rB.x = fmaxf((sB.x + o4) * scale, 0.f);
  rB.y = fmaxf((sB.y + o5) * scale, 0.f);
  rB.z = fmaxf((sB.z + o6) * scale, 0.f);
  rB.w = fmaxf((sB.w + o7) * scale, 0.f);
  if (lane < 16) {  // 16 lanes x 8 dims = full 128-dim row
    float* fp = feats + ((long)k * B + b) * E_DIM + j * 8;
    *(float4*)fp = rA;
    *(float4*)(fp + 4) = rB;
    *(float4*)(&sc[wv][j * 8]) = rA;
    *(float4*)(&sc[wv][j * 8 + 4]) = rB;
  }
  __syncthreads();

  // ---- inter(): hid[j] = b0[j] + sum_e r[e] * W0[e][j] ----
  float hid = b0[lane];
#pragma unroll 4
  for (int e = 0; e < E_DIM; ++e) hid += sc[wv][e] * W0[e * HDIM + lane];
  const float pp = tanhf(hid) * w1[lane];
  const float sum = waveSum(pp);
  if (lane == 0) partials[(long)k * B + b] = sum;
}

// Fallback (proven R4 kernel): fp32 gathers, used only if ws is too small.
__global__ __launch_bounds__(256) void phase1_f32(
    const float* __restrict__ user_embs, const float* __restrict__ item_embs,
    const float* __restrict__ w_uu, const float* __restrict__ w_uiu,
    const float* __restrict__ w_uui, const float* __restrict__ W0,
    const float* __restrict__ b0, const float* __restrict__ w1,
    const int* __restrict__ uid, const int* __restrict__ nbr,
    const int* __restrict__ uiu, const int* __restrict__ uui,
    float* __restrict__ feats, float* __restrict__ partials, int B) {
  const int lane = threadIdx.x & 63;
  const int wv = threadIdx.x >> 6;
  const int w_id = blockIdx.x * 4 + wv;
  const int b = w_id / 3;
  const int k = w_id - 3 * b;
  if (b >= B) return;

  __shared__ float sc[4][E_DIM];
  const int u = uid[b];
  const float self0 = user_embs[u * E_DIM + lane];
  const float self1 = user_embs[u * E_DIM + 64 + lane];
  const float* w = (k == 0) ? w_uu : (k == 1) ? w_uiu : w_uui;
  const float wa0 = w[lane], wa1 = w[64 + lane];
  const float wb0 = w[128 + lane], wb1 = w[192 + lane];
  const float logit_self = waveSum(self0 * wa0 + self1 * wa1);
  const bool is_uu = (k == 0);
  const float scale = is_uu ? 0.5f : (1.0f / 3.0f);
  const float* t0 = (k == 1) ? item_embs : user_embs;
  const float* t1 = (k == 1) ? user_embs : item_embs;
  int i0_l, i1_l;
  if (is_uu) {
    i0_l = nbr[b * L_DIM + lane];
    i1_l = 0;
  } else {
    const int* mp = (k == 1) ? uiu : uui;
    i0_l = mp[(b * 2 + 0) * L_DIM + lane];
    i1_l = mp[(b * 2 + 1) * L_DIM + lane];
  }
  const float mask_l = (i0_l == 0) ? 1.0f : 0.0f;
  float m = -3.0e38f, s = 0.0f, o0 = 0.0f, o1 = 0.0f;
  int i0 = __shfl(i0_l, 0), i1 = __shfl(i1_l, 0);
  float g00 = t0[i0 * E_DIM + lane];
  float g01 = t0[i0 * E_DIM + 64 + lane];
  float g10 = 0.f, g11 = 0.f;
  if (!is_uu) {
    g10 = t1[i1 * E_DIM + lane];
    g11 = t1[i1 * E_DIM + 64 + lane];
  }
  for (int l = 0; l < L_DIM; ++l) {
    const float f0 = (self0 + g00 + g10) * scale;
    const float f1 = (self1 + g01 + g11) * scale;
    if (l < L_DIM - 1) {
      i0 = __shfl(i0_l, l + 1);
      i1 = __shfl(i1_l, l + 1);
      g00 = t0[i0 * E_DIM + lane];
      g01 = t0[i0 * E_DIM + 64 + lane];
      if (!is_uu) {
        g10 = t1[i1 * E_DIM + lane];
        g11 = t1[i1 * E_DIM + 64 + lane];
      }
    }
    float logit = waveSum(f0 * wb0 + f1 * wb1) + logit_self;
    logit = (logit > 0.f) ? logit : 0.01f * logit;
    logit += -100000000.0f * __shfl(mask_l, l);
    const float mn = fmaxf(m, logit);
    const float alpha = __expf(m - mn);
    const float p = __expf(logit - mn);
    s = s * alpha + p;
    o0 = o0 * alpha + p * f0;
    o1 = o1 * alpha + p * f1;
    m = mn;
  }
  const float inv_s = 1.0f / s;
  const float r0 = fmaxf(o0 * inv_s, 0.f);
  const float r1 = fmaxf(o1 * inv_s, 0.f);
  feats[((long)k * B + b) * E_DIM + lane] = r0;
  feats[((long)k * B + b) * E_DIM + 64 + lane] = r1;
  sc[wv][lane] = r0;
  sc[wv][64 + lane] = r1;
  __syncthreads();
  float hid = b0[lane];
#pragma unroll 4
  for (int e = 0; e < E_DIM; ++e) hid += sc[wv][e] * W0[e * HDIM + lane];
  const float p = tanhf(hid) * w1[lane];
  const float sum = waveSum(p);
  if (lane == 0) partials[(long)k * B + b] = sum;
}

__global__ __launch_bounds__(256) void reduce_scores(
    const float* __restrict__ partials, float* __restrict__ weights, int B) {
  __shared__ float red[256];
  const int tid = threadIdx.x;
  float s[3];
#pragma unroll
  for (int k = 0; k < 3; ++k) {
    float acc = 0.f;
    for (int i = tid; i < B; i += 256) acc += partials[(long)k * B + i];
    red[tid] = acc;
    __syncthreads();
    for (int off = 128; off > 0; off >>= 1) {
      if (tid < off) red[tid] += red[tid + off];
      __syncthreads();
    }
    s[k] = red[0];
    __syncthreads();
  }
  if (tid == 0) {
    const float inv_b = 1.0f / (float)B;
    const float s0 = s[0] * inv_b, s1 = s[1] * inv_b, s2 = s[2] * inv_b;
    const float m = fmaxf(s0, fmaxf(s1, s2));
    const float e0 = __expf(s0 - m);
    const float e1 = __expf(s1 - m);
    const float e2 = __expf(s2 - m);
    const float inv = 1.0f / (e0 + e1 + e2);
    weights[0] = e0 * inv;
    weights[1] = e1 * inv;
    weights[2] = e2 * inv;
  }
}

__global__ __launch_bounds__(256) void phase2(
    const float* __restrict__ feats, const float* __restrict__ weights,
    float* __restrict__ out, int B) {
  const int i = blockIdx.x * blockDim.x + threadIdx.x;
  const int n = B * E_DIM;
  if (i >= n) return;
  const float w0 = weights[0], w1 = weights[1], w2 = weights[2];
  const float v = w0 * feats[i] + w1 * feats[n + i] + w2 * feats[2 * n + i];
  out[i] = fmaxf(v, 0.f);
}

// Main-path phase2 (proven R2): every block REDUNDANTLY reduces
// partials[3][B] (48 KB, L2/L3-resident) -> block-local 3-way softmax ->
// grid-stride weighted combine. Zero inter-block communication.
__global__ __launch_bounds__(256) void phase2_fused(
    const float* __restrict__ partials, const float* __restrict__ feats,
    float* __restrict__ out, int B) {
  __shared__ float red[3][4];
  const int tid = threadIdx.x;
  const int lane = tid & 63;
  const int wv = tid >> 6;

  float s0 = 0.f, s1 = 0.f, s2 = 0.f;
  if ((B & 3) == 0) {
    const float4* p4 = (const float4*)partials;
    const int nb4 = B >> 2;
    for (int i = tid; i < nb4; i += 256) {
      const float4 v0 = p4[i];
      const float4 v1 = p4[nb4 + i];
      const float4 v2 = p4[2 * nb4 + i];
      s0 += (v0.x + v0.y) + (v0.z + v0.w);
      s1 += (v1.x + v1.y) + (v1.z + v1.w);
      s2 += (v2.x + v2.y) + (v2.z + v2.w);
    }
  } else {
    for (int i = tid; i < B; i += 256) {
      s0 += partials[i];
      s1 += partials[B + i];
      s2 += partials[2 * B + i];
    }
  }
  s0 = waveSum(s0);
  s1 = waveSum(s1);
  s2 = waveSum(s2);
  if (lane == 0) {
    red[0][wv] = s0;
    red[1][wv] = s1;
    red[2][wv] = s2;
  }
  __syncthreads();
  const float inv_b = 1.0f / (float)B;
  const float a0 = (red[0][0] + red[0][1] + red[0][2] + red[0][3]) * inv_b;
  const float a1 = (red[1][0] + red[1][1] + red[1][2] + red[1][3]) * inv_b;
  const float a2 = (red[2][0] + red[2][1] + red[2][2] + red[2][3]) * inv_b;
  const float m = fmaxf(a0, fmaxf(a1, a2));
  const float e0 = __expf(a0 - m);
  const float e1 = __expf(a1 - m);
  const float e2 = __expf(a2 - m);
  const float inv = 1.0f / (e0 + e1 + e2);
  const float w0 = e0 * inv, w1 = e1 * inv, w2 = e2 * inv;

  const int n4 = (B * E_DIM) >> 2;
  const float4* f4 = (const float4*)feats;
  float4* o4 = (float4*)out;
  for (int i = blockIdx.x * 256 + tid; i < n4; i += gridDim.x * 256) {
    const float4 x = f4[i];
    const float4 y = f4[n4 + i];
    const float4 z = f4[2 * n4 + i];
    float4 r;
    r.x = fmaxf(w0 * x.x + w1 * y.x + w2 * z.x, 0.f);
    r.y = fmaxf(w0 * x.y + w1 * y.y + w2 * z.y, 0.f);
    r.z = fmaxf(w0 * x.z + w1 * y.z + w2 * z.z, 0.f);
    r.w = fmaxf(w0 * x.w + w1 * y.w + w2 * z.w, 0.f);
    o4[i] = r;
  }
}

extern "C" void kernel_launch(void* const* d_in, const int* in_sizes, int n_in,
                              void* d_out, int out_size, void* d_ws,
                              size_t ws_size, hipStream_t stream) {
  const float* user_embs = (const float*)d_in[0];
  const float* item_embs = (const float*)d_in[1];
  const float* w_uu = (const float*)d_in[2];
  const float* w_uiu = (const float*)d_in[3];
  const float* w_uui = (const float*)d_in[4];
  const float* W0 = (const float*)d_in[5];
  const float* b0 = (const float*)d_in[6];
  const float* w1 = (const float*)d_in[7];
  const int* uid = (const int*)d_in[8];
  const int* nbr = (const int*)d_in[9];
  const int* uiu = (const int*)d_in[10];
  const int* uui = (const int*)d_in[11];
  const int B = in_sizes[8];
  const int nU = in_sizes[0];  // user table elems
  const int nI = in_sizes[1];  // item table elems
  const int nUr = nU / E_DIM;  // user rows
  const int nIr = nI / E_DIM;  // item rows

  float* ws = (float*)d_ws;
  float* partials = ws;            // [3][B]
  float* weights = ws + 3 * B;     // [3] (+pad) — fallback path only
  float* feats = ws + 3 * B + 64;  // [3][B][E]
  const size_t f32_floats = (size_t)3 * B + 64 + (size_t)3 * B * E_DIM;
  // int8 tables (1 B/elem), then {proj,scale} float2 arrays (8B-aligned)
  signed char* user_q = (signed char*)(ws + f32_floats);
  signed char* item_q = user_q + nU;
  size_t qwords = ((size_t)nU + nI + 3) / 4;  // table bytes in floats
  qwords += (qwords & 1);                     // keep float2 8B-aligned
  float2* qU0 = (float2*)(ws + f32_floats + qwords);
  float2* qU1 = qU0 + nUr;
  float2* qU2 = qU1 + nUr;
  float2* qI1 = qU2 + nUr;
  float2* qI2 = qI1 + nIr;
  const size_t need =
      (f32_floats + qwords + 2 * ((size_t)3 * nUr + 2 * nIr)) * 4;

  const int n_waves = 3 * B;
  const int n_blocks = (n_waves + 3) / 4;
  const int n = B * E_DIM;

  if (ws_size >= need) {
    const int conv_waves = (nUr + nIr + 1) / 2;  // 2 rows per wave
    convert_i8<<<(conv_waves + 3) / 4, 256, 0, stream>>>(
        user_embs, item_embs, user_q, item_q, w_uu, w_uiu, w_uui, qU0, qU1,
        qU2, qI1, qI2, nUr, nIr);
    phase1_i8<<<n_blocks, 256, 0, stream>>>(
        user_embs, user_q, item_q, qU0, qU1, qU2, qI1, qI2, w_uu, w_uiu,
        w_uui, W0, b0, w1, uid, nbr, uiu, uui, feats, partials, B);
    phase2_fused<<<256, 256, 0, stream>>>(partials, feats, (float*)d_out, B);
  } else {
    phase1_f32<<<n_blocks, 256, 0, stream>>>(user_embs, item_embs, w_uu,
                                             w_uiu, w_uui, W0, b0, w1, uid,
                                             nbr, uiu, uui, feats, partials, B);
    reduce_scores<<<1, 256, 0, stream>>>(partials, weights, B);
    phase2<<<(n + 255) / 256, 256, 0, stream>>>(feats, weights, (float*)d_out,
                                                B);
  }
}

// Round 7
// 180.709 us; speedup vs baseline: 1.0459x; 1.0237x over previous
//
#include <hip/hip_runtime.h>

#define E_DIM 128
#define L_DIM 64
#define HDIM 64

__device__ __forceinline__ float waveSum(float v) {
#pragma unroll
  for (int o = 32; o > 0; o >>= 1) v += __shfl_xor(v, o);
  return v;
}
__device__ __forceinline__ float waveMax(float v) {
#pragma unroll
  for (int o = 32; o > 0; o >>= 1) v = fmaxf(v, __shfl_xor(v, o));
  return v;
}
__device__ __forceinline__ float halfSum(float v) {  // reduce within 32 lanes
#pragma unroll
  for (int o = 16; o > 0; o >>= 1) v += __shfl_xor(v, o);
  return v;
}
__device__ __forceinline__ float halfMax(float v) {  // max within 32 lanes
#pragma unroll
  for (int o = 16; o > 0; o >>= 1) v = fmaxf(v, __shfl_xor(v, o));
  return v;
}

// ---------------------------------------------------------------------------
// R20. Ledger: R14 contended global atomics = +23 µs. R16 coop grid.sync =
// 2x worse (device-scope spin-storm). R17 int8 = -17% for -50% bytes.
// R18 window-halving = null. R19 {proj,scale} float2 merge = -3.7 µs
// (line-touch model directionally right, quantitatively weak).
// R20: the untested lever is MLP. Depth-1 prefetch = 2 outstanding
// gathers/wave; latency 400-900 cyc vs ~80 cyc compute/group -> stalls.
// (R13's "depth-2 neutral" was the bf16 BYTE-saturated regime - stale.)
// Change 1: depth-4 rolling prefetch (4 register sets, 16=4x4 unroll,
//   8 outstanding loads/wave, VGPR ~52 < 64 cliff).
// Change 2: cost-homogeneous blocks (k=0 waves grouped; was ~40% idle
//   tail for k=0 waves inside mixed blocks).
// ---------------------------------------------------------------------------

// Convert pass: half-wave h handles global row 2*gw+h; user rows first,
// then item rows. Lane j covers dims 4j..4j+3. Row max via halfMax
// butterfly; int8 quantize + pack 4/lane; projections from fp32 values;
// {proj, scale} written as float2 pairs (qU0/qU1/qU2 user, qI1/qI2 item).
__global__ __launch_bounds__(256) void convert_i8(
    const float* __restrict__ user_src, const float* __restrict__ item_src,
    signed char* __restrict__ user_q, signed char* __restrict__ item_q,
    const float* __restrict__ w_uu, const float* __restrict__ w_uiu,
    const float* __restrict__ w_uui, float2* __restrict__ qU0,
    float2* __restrict__ qU1, float2* __restrict__ qU2,
    float2* __restrict__ qI1, float2* __restrict__ qI2, int nUr, int nIr) {
  const int lane = threadIdx.x & 63;
  const int j = lane & 31;
  const int h = lane >> 5;
  const int gw = blockIdx.x * 4 + (threadIdx.x >> 6);
  const int r_all = gw * 2 + h;
  if (r_all >= nUr + nIr) return;

  const bool is_user = (r_all < nUr);
  const int r = is_user ? r_all : r_all - nUr;
  const float* src = is_user ? user_src : item_src;
  signed char* dst = is_user ? user_q : item_q;

  const float4 v = *(const float4*)(src + (long)r * E_DIM + j * 4);

  // ---- per-row absmax -> scale ----
  float am =
      fmaxf(fmaxf(fabsf(v.x), fabsf(v.y)), fmaxf(fabsf(v.z), fabsf(v.w)));
  am = halfMax(am);
  const float s = am * (1.0f / 127.0f);
  const float inv = (am > 0.f) ? 127.0f / am : 0.f;

  int q0 = __float2int_rn(v.x * inv);
  int q1 = __float2int_rn(v.y * inv);
  int q2 = __float2int_rn(v.z * inv);
  int q3 = __float2int_rn(v.w * inv);
  q0 = max(-127, min(127, q0));
  q1 = max(-127, min(127, q1));
  q2 = max(-127, min(127, q2));
  q3 = max(-127, min(127, q3));
  const unsigned int pk = (unsigned int)(q0 & 255) |
                          ((unsigned int)(q1 & 255) << 8) |
                          ((unsigned int)(q2 & 255) << 16) |
                          ((unsigned int)(q3 & 255) << 24);
  ((unsigned int*)dst)[(long)r * (E_DIM / 4) + j] = pk;

  // ---- projections from ORIGINAL fp32 values (reference-consistent) ----
  const float* wA = is_user ? w_uu : w_uiu;
  const float* wB = is_user ? w_uiu : w_uui;
  const float4 a4 = *(const float4*)(wA + E_DIM + j * 4);
  const float dA = halfSum(v.x * a4.x + v.y * a4.y + v.z * a4.z + v.w * a4.w);
  const float4 b4 = *(const float4*)(wB + E_DIM + j * 4);
  const float dB = halfSum(v.x * b4.x + v.y * b4.y + v.z * b4.z + v.w * b4.w);
  float dC = 0.f;
  if (is_user) {
    const float4 c4 = *(const float4*)(w_uui + E_DIM + j * 4);
    dC = halfSum(v.x * c4.x + v.y * c4.y + v.z * c4.z + v.w * c4.w);
  }
  if (j == 0) {
    if (is_user) {
      qU0[r] = make_float2(dA, s);
      qU1[r] = make_float2(dB, s);
      qU2[r] = make_float2(dC, s);
    } else {
      qI1[r] = make_float2(dA, s);
      qI2[r] = make_float2(dB, s);
    }
  }
}

// One wave per (b, k). Logits+scales from ONE float2 gather per table.
// Weighted sum: quarter-wave uint2 row loads (16-lane quarter = one 128B
// int8 row per instruction) with DEPTH-4 rolling prefetch (4 register
// sets A-D, 8 outstanding loads/wave). Cost-homogeneous wave mapping:
// w_id < B -> k=0 (single-table); else (b,1),(b,2) pairs. Per-row dequant
// scales folded into broadcast weight. NO global atomics (R14/R16).
__global__ __launch_bounds__(256) void phase1_i8(
    const float* __restrict__ user_embs,  // fp32 (self rows)
    const signed char* __restrict__ user_q,
    const signed char* __restrict__ item_q,
    const float2* __restrict__ qU0, const float2* __restrict__ qU1,
    const float2* __restrict__ qU2, const float2* __restrict__ qI1,
    const float2* __restrict__ qI2,
    const float* __restrict__ w_uu, const float* __restrict__ w_uiu,
    const float* __restrict__ w_uui, const float* __restrict__ W0,
    const float* __restrict__ b0, const float* __restrict__ w1,
    const int* __restrict__ uid, const int* __restrict__ nbr,
    const int* __restrict__ uiu, const int* __restrict__ uui,
    float* __restrict__ feats,     // [3][B][E]
    float* __restrict__ partials,  // [3][B]
    int B) {
  const int lane = threadIdx.x & 63;
  const int j = lane & 15;        // dim chunk: dims 8j..8j+7
  const int quarter = lane >> 4;  // 0..3: which row of a 4-row group
  const int wv = threadIdx.x >> 6;
  const int w_id = blockIdx.x * 4 + wv;
  if (w_id >= 3 * B) return;

  // cost-homogeneous mapping: first B waves are k=0; rest alternate k=1,2
  int b, k;
  if (w_id < B) {
    b = w_id;
    k = 0;
  } else {
    const int t = w_id - B;
    b = t >> 1;
    k = 1 + (t & 1);
  }

  __shared__ float sc[4][E_DIM];

  const bool is_uu = (k == 0);
  const float scale = is_uu ? 0.5f : (1.0f / 3.0f);
  // tables: k==0 -> user; k==1 (uiu) -> item,user; k==2 (uui) -> user,item
  const uint2* T0 = (const uint2*)((k == 1) ? item_q : user_q);
  const uint2* T1 = (const uint2*)((k == 1) ? user_q : item_q);
  const float2* P0 = (k == 0) ? qU0 : (k == 1) ? qI1 : qU2;
  const float2* P1 = (k == 1) ? qU1 : qI2;  // unused for k==0

  // ---- issue index + {proj,scale} gathers FIRST ----
  int i0_l, i1_l;
  if (is_uu) {
    i0_l = nbr[b * L_DIM + lane];
    i1_l = 0;
  } else {
    const int* mp = (k == 1) ? uiu : uui;
    i0_l = mp[(b * 2 + 0) * L_DIM + lane];
    i1_l = mp[(b * 2 + 1) * L_DIM + lane];
  }
  const float2 ps0 = P0[i0_l];  // {proj, dequant scale}
  float2 ps1 = make_float2(0.f, 0.f);
  if (!is_uu) ps1 = P1[i1_l];

  const int u = uid[b];
  const float2 self2 = *(const float2*)(user_embs + (long)u * E_DIM + lane * 2);

  const float* w = (k == 0) ? w_uu : (k == 1) ? w_uiu : w_uui;
  const float2 wa = *(const float2*)(w + lane * 2);
  const float2 wb = *(const float2*)(w + E_DIM + lane * 2);
  const float S1 = waveSum(self2.x * wa.x + self2.y * wa.y);
  const float S2 = waveSum(self2.x * wb.x + self2.y * wb.y);

  // ---- logits from projections ----
  float d = ps0.x;
  if (!is_uu) d += ps1.x;
  float logit = S1 + scale * (S2 + d);
  logit = (logit > 0.f) ? logit : 0.01f * logit;  // leaky_relu
  if (i0_l == 0) logit += -100000000.0f;          // mask

  const float M = waveMax(logit);
  const float p = __expf(logit - M);
  const float Z = waveSum(p);
  const float a_l = p / Z;  // lane l: neighbor l's attention weight

  // fold per-row dequant scales into the weights (lane = neighbor)
  const float as0_l = a_l * ps0.y;
  const float as1_l = is_uu ? 0.f : a_l * ps1.y;

  // ---- weighted sum: 4 rows/instr (quarter-wave uint2), DEPTH-4 ----
  constexpr int RQ = E_DIM / 8;  // 16 uint2 per 128B int8 row
  float o0 = 0.f, o1 = 0.f, o2 = 0.f, o3 = 0.f;
  float o4 = 0.f, o5 = 0.f, o6 = 0.f, o7 = 0.f;

  auto LD = [&](int g, float& w0o, float& w1o, uint2& r0o, uint2& r1o) {
    const int l4 = 4 * g + quarter;
    w0o = __shfl(as0_l, l4);
    const int i0g = __shfl(i0_l, l4);
    r0o = T0[(long)i0g * RQ + j];
    if (!is_uu) {
      w1o = __shfl(as1_l, l4);
      const int i1g = __shfl(i1_l, l4);
      r1o = T1[(long)i1g * RQ + j];
    } else {
      w1o = 0.f;
      r1o = make_uint2(0u, 0u);
    }
  };
  auto FMA8 = [&](float a0, float a1, uint2 qa, uint2 qb) {
    o0 += a0 * (float)(signed char)(qa.x);
    o1 += a0 * (float)(signed char)(qa.x >> 8);
    o2 += a0 * (float)(signed char)(qa.x >> 16);
    o3 += a0 * (float)((int)qa.x >> 24);
    o4 += a0 * (float)(signed char)(qa.y);
    o5 += a0 * (float)(signed char)(qa.y >> 8);
    o6 += a0 * (float)(signed char)(qa.y >> 16);
    o7 += a0 * (float)((int)qa.y >> 24);
    if (!is_uu) {
      o0 += a1 * (float)(signed char)(qb.x);
      o1 += a1 * (float)(signed char)(qb.x >> 8);
      o2 += a1 * (float)(signed char)(qb.x >> 16);
      o3 += a1 * (float)((int)qb.x >> 24);
      o4 += a1 * (float)(signed char)(qb.y);
      o5 += a1 * (float)(signed char)(qb.y >> 8);
      o6 += a1 * (float)(signed char)(qb.y >> 16);
      o7 += a1 * (float)((int)qb.y >> 24);
    }
  };

  float aA0, aA1, aB0, aB1, aC0, aC1, aD0, aD1;
  uint2 qA0, qA1, qB0, qB1, qC0, qC1, qD0, qD1;
  LD(0, aA0, aA1, qA0, qA1);
  LD(1, aB0, aB1, qB0, qB1);
  LD(2, aC0, aC1, qC0, qC1);
  LD(3, aD0, aD1, qD0, qD1);
#pragma unroll
  for (int it = 0; it < L_DIM / 4; it += 4) {
    {
      const float a0 = aA0, a1 = aA1;
      const uint2 qa = qA0, qb = qA1;
      if (it + 4 < L_DIM / 4) LD(it + 4, aA0, aA1, qA0, qA1);
      FMA8(a0, a1, qa, qb);
    }
    {
      const float a0 = aB0, a1 = aB1;
      const uint2 qa = qB0, qb = qB1;
      if (it + 5 < L_DIM / 4) LD(it + 5, aB0, aB1, qB0, qB1);
      FMA8(a0, a1, qa, qb);
    }
    {
      const float a0 = aC0, a1 = aC1;
      const uint2 qa = qC0, qb = qC1;
      if (it + 6 < L_DIM / 4) LD(it + 6, aC0, aC1, qC0, qC1);
      FMA8(a0, a1, qa, qb);
    }
    {
      const float a0 = aD0, a1 = aD1;
      const uint2 qa = qD0, qb = qD1;
      if (it + 7 < L_DIM / 4) LD(it + 7, aD0, aD1, qD0, qD1);
      FMA8(a0, a1, qa, qb);
    }
  }
  // combine the 4 quarters (each summed 16 of the 64 neighbors)
  o0 += __shfl_xor(o0, 16); o0 += __shfl_xor(o0, 32);
  o1 += __shfl_xor(o1, 16); o1 += __shfl_xor(o1, 32);
  o2 += __shfl_xor(o2, 16); o2 += __shfl_xor(o2, 32);
  o3 += __shfl_xor(o3, 16); o3 += __shfl_xor(o3, 32);
  o4 += __shfl_xor(o4, 16); o4 += __shfl_xor(o4, 32);
  o5 += __shfl_xor(o5, 16); o5 += __shfl_xor(o5, 32);
  o6 += __shfl_xor(o6, 16); o6 += __shfl_xor(o6, 32);
  o7 += __shfl_xor(o7, 16); o7 += __shfl_xor(o7, 32);

  // sum_l a_l = 1  =>  out = scale * (self + sum as0*q0 [+ as1*q1])
  const float4 sA = *(const float4*)(user_embs + (long)u * E_DIM + j * 8);
  const float4 sB = *(const float4*)(user_embs + (long)u * E_DIM + j * 8 + 4);
  float4 rA, rB;
  rA.x = fmaxf((sA.x + o0) * scale, 0.f);
  rA.y = fmaxf((sA.y + o1) * scale, 0.f);
  rA.z = fmaxf((sA.z + o2) * scale, 0.f);
  rA.w = fmaxf((sA.w + o3) * scale, 0.f);
  rB.x = fmaxf((sB.x + o4) * scale, 0.f);
  rB.y = fmaxf((sB.y + o5) * scale, 0.f);
  rB.z = fmaxf((sB.z + o6) * scale, 0.f);
  rB.w = fmaxf((sB.w + o7) * scale, 0.f);
  if (lane < 16) {  // 16 lanes x 8 dims = full 128-dim row
    float* fp = feats + ((long)k * B + b) * E_DIM + j * 8;
    *(float4*)fp = rA;
    *(float4*)(fp + 4) = rB;
    *(float4*)(&sc[wv][j * 8]) = rA;
    *(float4*)(&sc[wv][j * 8 + 4]) = rB;
  }
  __syncthreads();

  // ---- inter(): hid[j] = b0[j] + sum_e r[e] * W0[e][j] ----
  float hid = b0[lane];
#pragma unroll 4
  for (int e = 0; e < E_DIM; ++e) hid += sc[wv][e] * W0[e * HDIM + lane];
  const float pp = tanhf(hid) * w1[lane];
  const float sum = waveSum(pp);
  if (lane == 0) partials[(long)k * B + b] = sum;
}

// Fallback (proven R4 kernel): fp32 gathers, used only if ws is too small.
__global__ __launch_bounds__(256) void phase1_f32(
    const float* __restrict__ user_embs, const float* __restrict__ item_embs,
    const float* __restrict__ w_uu, const float* __restrict__ w_uiu,
    const float* __restrict__ w_uui, const float* __restrict__ W0,
    const float* __restrict__ b0, const float* __restrict__ w1,
    const int* __restrict__ uid, const int* __restrict__ nbr,
    const int* __restrict__ uiu, const int* __restrict__ uui,
    float* __restrict__ feats, float* __restrict__ partials, int B) {
  const int lane = threadIdx.x & 63;
  const int wv = threadIdx.x >> 6;
  const int w_id = blockIdx.x * 4 + wv;
  const int b = w_id / 3;
  const int k = w_id - 3 * b;
  if (b >= B) return;

  __shared__ float sc[4][E_DIM];
  const int u = uid[b];
  const float self0 = user_embs[u * E_DIM + lane];
  const float self1 = user_embs[u * E_DIM + 64 + lane];
  const float* w = (k == 0) ? w_uu : (k == 1) ? w_uiu : w_uui;
  const float wa0 = w[lane], wa1 = w[64 + lane];
  const float wb0 = w[128 + lane], wb1 = w[192 + lane];
  const float logit_self = waveSum(self0 * wa0 + self1 * wa1);
  const bool is_uu = (k == 0);
  const float scale = is_uu ? 0.5f : (1.0f / 3.0f);
  const float* t0 = (k == 1) ? item_embs : user_embs;
  const float* t1 = (k == 1) ? user_embs : item_embs;
  int i0_l, i1_l;
  if (is_uu) {
    i0_l = nbr[b * L_DIM + lane];
    i1_l = 0;
  } else {
    const int* mp = (k == 1) ? uiu : uui;
    i0_l = mp[(b * 2 + 0) * L_DIM + lane];
    i1_l = mp[(b * 2 + 1) * L_DIM + lane];
  }
  const float mask_l = (i0_l == 0) ? 1.0f : 0.0f;
  float m = -3.0e38f, s = 0.0f, o0 = 0.0f, o1 = 0.0f;
  int i0 = __shfl(i0_l, 0), i1 = __shfl(i1_l, 0);
  float g00 = t0[i0 * E_DIM + lane];
  float g01 = t0[i0 * E_DIM + 64 + lane];
  float g10 = 0.f, g11 = 0.f;
  if (!is_uu) {
    g10 = t1[i1 * E_DIM + lane];
    g11 = t1[i1 * E_DIM + 64 + lane];
  }
  for (int l = 0; l < L_DIM; ++l) {
    const float f0 = (self0 + g00 + g10) * scale;
    const float f1 = (self1 + g01 + g11) * scale;
    if (l < L_DIM - 1) {
      i0 = __shfl(i0_l, l + 1);
      i1 = __shfl(i1_l, l + 1);
      g00 = t0[i0 * E_DIM + lane];
      g01 = t0[i0 * E_DIM + 64 + lane];
      if (!is_uu) {
        g10 = t1[i1 * E_DIM + lane];
        g11 = t1[i1 * E_DIM + 64 + lane];
      }
    }
    float logit = waveSum(f0 * wb0 + f1 * wb1) + logit_self;
    logit = (logit > 0.f) ? logit : 0.01f * logit;
    logit += -100000000.0f * __shfl(mask_l, l);
    const float mn = fmaxf(m, logit);
    const float alpha = __expf(m - mn);
    const float p = __expf(logit - mn);
    s = s * alpha + p;
    o0 = o0 * alpha + p * f0;
    o1 = o1 * alpha + p * f1;
    m = mn;
  }
  const float inv_s = 1.0f / s;
  const float r0 = fmaxf(o0 * inv_s, 0.f);
  const float r1 = fmaxf(o1 * inv_s, 0.f);
  feats[((long)k * B + b) * E_DIM + lane] = r0;
  feats[((long)k * B + b) * E_DIM + 64 + lane] = r1;
  sc[wv][lane] = r0;
  sc[wv][64 + lane] = r1;
  __syncthreads();
  float hid = b0[lane];
#pragma unroll 4
  for (int e = 0; e < E_DIM; ++e) hid += sc[wv][e] * W0[e * HDIM + lane];
  const float p = tanhf(hid) * w1[lane];
  const float sum = waveSum(p);
  if (lane == 0) partials[(long)k * B + b] = sum;
}

__global__ __launch_bounds__(256) void reduce_scores(
    const float* __restrict__ partials, float* __restrict__ weights, int B) {
  __shared__ float red[256];
  const int tid = threadIdx.x;
  float s[3];
#pragma unroll
  for (int k = 0; k < 3; ++k) {
    float acc = 0.f;
    for (int i = tid; i < B; i += 256) acc += partials[(long)k * B + i];
    red[tid] = acc;
    __syncthreads();
    for (int off = 128; off > 0; off >>= 1) {
      if (tid < off) red[tid] += red[tid + off];
      __syncthreads();
    }
    s[k] = red[0];
    __syncthreads();
  }
  if (tid == 0) {
    const float inv_b = 1.0f / (float)B;
    const float s0 = s[0] * inv_b, s1 = s[1] * inv_b, s2 = s[2] * inv_b;
    const float m = fmaxf(s0, fmaxf(s1, s2));
    const float e0 = __expf(s0 - m);
    const float e1 = __expf(s1 - m);
    const float e2 = __expf(s2 - m);
    const float inv = 1.0f / (e0 + e1 + e2);
    weights[0] = e0 * inv;
    weights[1] = e1 * inv;
    weights[2] = e2 * inv;
  }
}

__global__ __launch_bounds__(256) void phase2(
    const float* __restrict__ feats, const float* __restrict__ weights,
    float* __restrict__ out, int B) {
  const int i = blockIdx.x * blockDim.x + threadIdx.x;
  const int n = B * E_DIM;
  if (i >= n) return;
  const float w0 = weights[0], w1 = weights[1], w2 = weights[2];
  const float v = w0 * feats[i] + w1 * feats[n + i] + w2 * feats[2 * n + i];
  out[i] = fmaxf(v, 0.f);
}

// Main-path phase2 (proven R2): every block REDUNDANTLY reduces
// partials[3][B] (48 KB, L2/L3-resident) -> block-local 3-way softmax ->
// grid-stride weighted combine. Zero inter-block communication.
__global__ __launch_bounds__(256) void phase2_fused(
    const float* __restrict__ partials, const float* __restrict__ feats,
    float* __restrict__ out, int B) {
  __shared__ float red[3][4];
  const int tid = threadIdx.x;
  const int lane = tid & 63;
  const int wv = tid >> 6;

  float s0 = 0.f, s1 = 0.f, s2 = 0.f;
  if ((B & 3) == 0) {
    const float4* p4 = (const float4*)partials;
    const int nb4 = B >> 2;
    for (int i = tid; i < nb4; i += 256) {
      const float4 v0 = p4[i];
      const float4 v1 = p4[nb4 + i];
      const float4 v2 = p4[2 * nb4 + i];
      s0 += (v0.x + v0.y) + (v0.z + v0.w);
      s1 += (v1.x + v1.y) + (v1.z + v1.w);
      s2 += (v2.x + v2.y) + (v2.z + v2.w);
    }
  } else {
    for (int i = tid; i < B; i += 256) {
      s0 += partials[i];
      s1 += partials[B + i];
      s2 += partials[2 * B + i];
    }
  }
  s0 = waveSum(s0);
  s1 = waveSum(s1);
  s2 = waveSum(s2);
  if (lane == 0) {
    red[0][wv] = s0;
    red[1][wv] = s1;
    red[2][wv] = s2;
  }
  __syncthreads();
  const float inv_b = 1.0f / (float)B;
  const float a0 = (red[0][0] + red[0][1] + red[0][2] + red[0][3]) * inv_b;
  const float a1 = (red[1][0] + red[1][1] + red[1][2] + red[1][3]) * inv_b;
  const float a2 = (red[2][0] + red[2][1] + red[2][2] + red[2][3]) * inv_b;
  const float m = fmaxf(a0, fmaxf(a1, a2));
  const float e0 = __expf(a0 - m);
  const float e1 = __expf(a1 - m);
  const float e2 = __expf(a2 - m);
  const float inv = 1.0f / (e0 + e1 + e2);
  const float w0 = e0 * inv, w1 = e1 * inv, w2 = e2 * inv;

  const int n4 = (B * E_DIM) >> 2;
  const float4* f4 = (const float4*)feats;
  float4* o4 = (float4*)out;
  for (int i = blockIdx.x * 256 + tid; i < n4; i += gridDim.x * 256) {
    const float4 x = f4[i];
    const float4 y = f4[n4 + i];
    const float4 z = f4[2 * n4 + i];
    float4 r;
    r.x = fmaxf(w0 * x.x + w1 * y.x + w2 * z.x, 0.f);
    r.y = fmaxf(w0 * x.y + w1 * y.y + w2 * z.y, 0.f);
    r.z = fmaxf(w0 * x.z + w1 * y.z + w2 * z.z, 0.f);
    r.w = fmaxf(w0 * x.w + w1 * y.w + w2 * z.w, 0.f);
    o4[i] = r;
  }
}

extern "C" void kernel_launch(void* const* d_in, const int* in_sizes, int n_in,
                              void* d_out, int out_size, void* d_ws,
                              size_t ws_size, hipStream_t stream) {
  const float* user_embs = (const float*)d_in[0];
  const float* item_embs = (const float*)d_in[1];
  const float* w_uu = (const float*)d_in[2];
  const float* w_uiu = (const float*)d_in[3];
  const float* w_uui = (const float*)d_in[4];
  const float* W0 = (const float*)d_in[5];
  const float* b0 = (const float*)d_in[6];
  const float* w1 = (const float*)d_in[7];
  const int* uid = (const int*)d_in[8];
  const int* nbr = (const int*)d_in[9];
  const int* uiu = (const int*)d_in[10];
  const int* uui = (const int*)d_in[11];
  const int B = in_sizes[8];
  const int nU = in_sizes[0];  // user table elems
  const int nI = in_sizes[1];  // item table elems
  const int nUr = nU / E_DIM;  // user rows
  const int nIr = nI / E_DIM;  // item rows

  float* ws = (float*)d_ws;
  float* partials = ws;            // [3][B]
  float* weights = ws + 3 * B;     // [3] (+pad) — fallback path only
  float* feats = ws + 3 * B + 64;  // [3][B][E]
  const size_t f32_floats = (size_t)3 * B + 64 + (size_t)3 * B * E_DIM;
  // int8 tables (1 B/elem), then {proj,scale} float2 arrays (8B-aligned)
  signed char* user_q = (signed char*)(ws + f32_floats);
  signed char* item_q = user_q + nU;
  size_t qwords = ((size_t)nU + nI + 3) / 4;  // table bytes in floats
  qwords += (qwords & 1);                     // keep float2 8B-aligned
  float2* qU0 = (float2*)(ws + f32_floats + qwords);
  float2* qU1 = qU0 + nUr;
  float2* qU2 = qU1 + nUr;
  float2* qI1 = qU2 + nUr;
  float2* qI2 = qI1 + nIr;
  const size_t need =
      (f32_floats + qwords + 2 * ((size_t)3 * nUr + 2 * nIr)) * 4;

  const int n_waves = 3 * B;
  const int n_blocks = (n_waves + 3) / 4;
  const int n = B * E_DIM;

  if (ws_size >= need) {
    const int conv_waves = (nUr + nIr + 1) / 2;  // 2 rows per wave
    convert_i8<<<(conv_waves + 3) / 4, 256, 0, stream>>>(
        user_embs, item_embs, user_q, item_q, w_uu, w_uiu, w_uui, qU0, qU1,
        qU2, qI1, qI2, nUr, nIr);
    phase1_i8<<<n_blocks, 256, 0, stream>>>(
        user_embs, user_q, item_q, qU0, qU1, qU2, qI1, qI2, w_uu, w_uiu,
        w_uui, W0, b0, w1, uid, nbr, uiu, uui, feats, partials, B);
    phase2_fused<<<256, 256, 0, stream>>>(partials, feats, (float*)d_out, B);
  } else {
    phase1_f32<<<n_blocks, 256, 0, stream>>>(user_embs, item_embs, w_uu,
                                             w_uiu, w_uui, W0, b0, w1, uid,
                                             nbr, uiu, uui, feats, partials, B);
    reduce_scores<<<1, 256, 0, stream>>>(partials, weights, B);
    phase2<<<(n + 255) / 256, 256, 0, stream>>>(feats, weights, (float*)d_out,
                                                B);
  }
}